// Round 2
// baseline (438.569 us; speedup 1.0000x reference)
//
#include <hip/hip_runtime.h>

// ExtractTensorPatches: x (16,3,512,512) f32, window 16x16, stride 8x8, pad 0.
// out (16, 63*63, 3, 16, 16) f32.
//
// Producer-driven scatter. Key fact: window/stride/f4 alignment (8, 4 | 16)
// means each input float4 x[b][c][row][4*col4 ..] appears VERBATIM in at most
// 4 output slots: vertical copies ph = row>>3 (i = row&7) and ph-1 (i = i+8),
// horizontal copies pw = col4>>1 (slot = col4&1) and pw-1 (slot += 2).
// So: 1 coalesced f4 load per thread (input fetched exactly once, 50 MB),
// up to 4 nontemporal 16B stores (each output element written exactly once,
// 195 MB). No LDS, no barrier, low VGPR -> full occupancy, 12288 blocks.
// Adjacent even/odd lanes write slots 0/1 (and 2/3) of the same patch ->
// 32B-contiguous store pairs across lanes; the two 32B halves of each 64B
// output line come from back-to-back stores of the same wave -> merge in L2.

#define BB 16
#define CC 3
#define HH 512
#define WW 512
#define NH 63
#define NW 63
#define NP (NH * NW)

typedef float f4 __attribute__((ext_vector_type(4)));

__global__ __launch_bounds__(256) void scatter_patches(
    const float* __restrict__ x, float* __restrict__ out) {
  unsigned int blk = blockIdx.x;
  unsigned int tid = threadIdx.x;

  // 65536 float4 per (b,c) plane; 256 blocks per plane; block covers 2 rows.
  unsigned int plane = blk >> 8;                  // b*3 + c, 0..47
  unsigned int b = plane / CC;
  unsigned int c = plane - b * CC;
  unsigned int row  = ((blk & 255u) << 1) | (tid >> 7);  // 0..511
  unsigned int col4 = tid & 127u;                 // float4 column, 0..127

  const f4* src = reinterpret_cast<const f4*>(x);
  f4 v = src[(plane << 16) + (row << 7) + col4];  // 1KB/wave, coalesced

  f4* o = reinterpret_cast<f4*>(out);
  // out f4 index = ((b*NP + ph*NW + pw)*CC + c)*64 + i*4 + s
  unsigned int base = b * (NP * CC * 64u) + c * 64u;     // b*762048 + c*64

  unsigned int ph1 = row >> 3;                    // i1 = row & 7
  unsigned int i1  = row & 7u;
  unsigned int a1 = base + ph1 * (NW * CC * 64u) + (i1 << 2);
  // ph2 = ph1-1, i2 = i1+8:  a2 = a1 - 12096 + 32
  unsigned int a2 = a1 - (NW * CC * 64u) + 32u;

  unsigned int offA = (col4 >> 1) * (CC * 64u) + (col4 & 1u);  // pwA*192 + sA
  // pwB = pwA-1, sB = sA+2:  offB = offA - 192 + 2
  unsigned int offB = offA - (CC * 64u) + 2u;

  bool r1 = row < (HH - 8u);   // ph1 <= 62
  bool r2 = row >= 8u;         // ph2 >= 0
  bool ca = col4 < 126u;       // pwA <= 62
  bool cb = col4 >= 2u;        // pwB >= 0

  if (r1 & ca) __builtin_nontemporal_store(v, &o[a1 + offA]);
  if (r1 & cb) __builtin_nontemporal_store(v, &o[a1 + offB]);
  if (r2 & ca) __builtin_nontemporal_store(v, &o[a2 + offA]);
  if (r2 & cb) __builtin_nontemporal_store(v, &o[a2 + offB]);
}

extern "C" void kernel_launch(void* const* d_in, const int* in_sizes, int n_in,
                              void* d_out, int out_size, void* d_ws, size_t ws_size,
                              hipStream_t stream) {
  const float* x = (const float*)d_in[0];
  float* out = (float*)d_out;
  scatter_patches<<<dim3(BB * CC * 256), 256, 0, stream>>>(x, out);
}

// Round 3
// 231.448 us; speedup vs baseline: 1.8949x; 1.8949x over previous
//
#include <hip/hip_runtime.h>

// ExtractTensorPatches: x (16,3,512,512) f32, window 16x16, stride 8x8, pad 0.
// out (16, 63*63, 3, 16, 16) f32.
//
// v3: LDS-staged strips (wave-contiguous 1KB stores — the scatter experiment
// proved partial-line scattered stores cost 1.57x write amplification and
// 2.6x time). Improvements over the 227us baseline:
//  - G=3 ph per block: stage 32 rows (64KB) once, emit 3*63 patches.
//    Input fetch 97MB -> 64.5MB, 3x fewer barriers.
//  - XCD-bijective block remap (1008 = 8*126): adjacent-g blocks (sharing 8
//    boundary rows) run on the same XCD -> L2 hits on the overlap.
//  - XOR swizzle (col4 ^= (row&3)<<1) instead of row padding: emit-phase
//    ds_read_b128 goes from 4-way (LDSW=520) to <=2-way (free) bank access;
//    staging writes stay stride-1 conflict-free.

#define BB 16
#define CC 3
#define HH 512
#define WW 512
#define NH 63
#define NW 63
#define NP (NH * NW)
#define G 3
#define NG (NH / G)        // 21 groups of ph
#define ROWS (8 * G + 8)   // 32 rows staged per block
#define TPB 512

typedef float f4 __attribute__((ext_vector_type(4)));

__device__ __forceinline__ unsigned swz(unsigned row, unsigned col4) {
  return col4 ^ ((row & 3u) << 1);  // permutes within a 128-f4 row
}

__global__ __launch_bounds__(TPB) void extract_patches_v3(
    const float* __restrict__ x, float* __restrict__ out) {
  __shared__ f4 lds[ROWS * 128];  // 64 KB -> 2 blocks/CU, 16 waves/CU

  // XCD-contiguous bijective remap: 1008 blocks = 8 XCDs * 126.
  unsigned blk = blockIdx.x;
  unsigned id = (blk & 7u) * (BB * CC * NG / 8u) + (blk >> 3);

  unsigned plane = id / NG;  // b*3 + c
  unsigned g = id - plane * NG;
  unsigned b = plane / CC;
  unsigned c = plane - b * CC;
  unsigned tid = threadIdx.x;

  // ---- Stage rows [24g, 24g+32) of x[b][c]: 64KB contiguous, coalesced.
  const f4* src = reinterpret_cast<const f4*>(x) +
                  (((size_t)plane << 9) + 24u * g) * 128u;
  #pragma unroll
  for (int k = 0; k < 8; ++k) {
    unsigned idx = tid + (unsigned)k * TPB;  // 0..4095 f4
    unsigned row = idx >> 7;
    unsigned col4 = idx & 127u;
    lds[row * 128u + swz(row, col4)] = src[idx];
  }
  __syncthreads();

  // ---- Emit 3*63 patches. e = (h*63 + pw)*64 + r; wave = one patch = 1KB.
  f4* o = reinterpret_cast<f4*>(out);
  size_t obase = ((size_t)b * NP + (size_t)(3u * g) * NW) * (CC * 64u) +
                 (size_t)c * 64u;
  for (unsigned e = tid; e < 3u * NW * 64u; e += TPB) {
    unsigned r = e & 63u;
    unsigned pq = e >> 6;        // h*63 + pw
    unsigned h = pq / NW;
    unsigned pw = pq - h * NW;
    unsigned i = r >> 2;
    unsigned j4 = r & 3u;
    unsigned lrow = 8u * h + i;
    f4 v = lds[lrow * 128u + swz(lrow, 2u * pw + j4)];
    __builtin_nontemporal_store(v, &o[obase + (size_t)pq * (CC * 64u) + r]);
  }
}

extern "C" void kernel_launch(void* const* d_in, const int* in_sizes, int n_in,
                              void* d_out, int out_size, void* d_ws, size_t ws_size,
                              hipStream_t stream) {
  const float* x = (const float*)d_in[0];
  float* out = (float*)d_out;
  extract_patches_v3<<<dim3(BB * CC * NG), TPB, 0, stream>>>(x, out);
}

// Round 4
// 231.315 us; speedup vs baseline: 1.8960x; 1.0006x over previous
//
#include <hip/hip_runtime.h>

// ExtractTensorPatches: x (16,3,512,512) f32, window 16x16, stride 8x8, pad 0.
// out (16, 63*63, 3, 16, 16) f32.
//
// v4 = v3 with PLAIN stores (the single variable under test).
// Evidence: scatter experiment's 32B nt stores showed 1.57x write
// amplification -> nt bypasses L2 write-combining on gfx950. All prior
// variants shared nt stores and all sat at ~2 TB/s effective writes while
// the plain-store fill kernel hits 6.5 TB/s. Input is L3-resident (FETCH
// 25MB < 50MB input), so L2/L3 pollution from cached output writes is moot.
//
// Structure (unchanged from v3):
//  - block = (b, c, g): stage 32 rows (64KB) once, emit 3*63 patches.
//  - XCD-bijective block remap (1008 = 8*126) for boundary-row L2 reuse.
//  - XOR swizzle (col4 ^= (row&3)<<1): conflict-free staging writes and
//    emit reads.

#define BB 16
#define CC 3
#define HH 512
#define WW 512
#define NH 63
#define NW 63
#define NP (NH * NW)
#define G 3
#define NG (NH / G)        // 21 groups of ph
#define ROWS (8 * G + 8)   // 32 rows staged per block
#define TPB 512

typedef float f4 __attribute__((ext_vector_type(4)));

__device__ __forceinline__ unsigned swz(unsigned row, unsigned col4) {
  return col4 ^ ((row & 3u) << 1);  // permutes within a 128-f4 row
}

__global__ __launch_bounds__(TPB) void extract_patches_v4(
    const float* __restrict__ x, float* __restrict__ out) {
  __shared__ f4 lds[ROWS * 128];  // 64 KB -> 2 blocks/CU, 16 waves/CU

  // XCD-contiguous bijective remap: 1008 blocks = 8 XCDs * 126.
  unsigned blk = blockIdx.x;
  unsigned id = (blk & 7u) * (BB * CC * NG / 8u) + (blk >> 3);

  unsigned plane = id / NG;  // b*3 + c
  unsigned g = id - plane * NG;
  unsigned b = plane / CC;
  unsigned c = plane - b * CC;
  unsigned tid = threadIdx.x;

  // ---- Stage rows [24g, 24g+32) of x[b][c]: 64KB contiguous, coalesced.
  const f4* src = reinterpret_cast<const f4*>(x) +
                  (((size_t)plane << 9) + 24u * g) * 128u;
  #pragma unroll
  for (int k = 0; k < 8; ++k) {
    unsigned idx = tid + (unsigned)k * TPB;  // 0..4095 f4
    unsigned row = idx >> 7;
    unsigned col4 = idx & 127u;
    lds[row * 128u + swz(row, col4)] = src[idx];
  }
  __syncthreads();

  // ---- Emit 3*63 patches. e = (h*63 + pw)*64 + r; wave = one patch = 1KB.
  f4* o = reinterpret_cast<f4*>(out);
  size_t obase = ((size_t)b * NP + (size_t)(3u * g) * NW) * (CC * 64u) +
                 (size_t)c * 64u;
  for (unsigned e = tid; e < 3u * NW * 64u; e += TPB) {
    unsigned r = e & 63u;
    unsigned pq = e >> 6;        // h*63 + pw
    unsigned h = pq / NW;
    unsigned pw = pq - h * NW;
    unsigned i = r >> 2;
    unsigned j4 = r & 3u;
    unsigned lrow = 8u * h + i;
    f4 v = lds[lrow * 128u + swz(lrow, 2u * pw + j4)];
    o[obase + (size_t)pq * (CC * 64u) + r] = v;  // plain store (A/B vs nt)
  }
}

extern "C" void kernel_launch(void* const* d_in, const int* in_sizes, int n_in,
                              void* d_out, int out_size, void* d_ws, size_t ws_size,
                              hipStream_t stream) {
  const float* x = (const float*)d_in[0];
  float* out = (float*)d_out;
  extract_patches_v4<<<dim3(BB * CC * NG), TPB, 0, stream>>>(x, out);
}

// Round 5
// 227.969 us; speedup vs baseline: 1.9238x; 1.0147x over previous
//
#include <hip/hip_runtime.h>

// ExtractTensorPatches: x (16,3,512,512) f32, window 16x16, stride 8x8, pad 0.
// out (16, 63*63, 3, 16, 16) f32.
//
// v5: contiguous-output blocking. Previous variants fixed c per block ->
// 1KB output chunks at 3KB stride, interleaved across blocks/XCDs (DRAM
// row-buffer thrash; nt-vs-plain A/B proved cache policy irrelevant).
// Output is contiguous across c for a fixed patch, so re-block:
//   block = (b, ph, half-of-pw): stage 16 rows x ~264 cols x ALL 3 channels
//   (50.7 KB LDS), emit 31-32 patches x 3KB = one fully LINEAR 93-96 KB
//   write stream per block — same stream shape as the 6.5 TB/s fill.
// Also: 3 blocks/CU (24 waves/CU, was 16), 2016 blocks, row stride 66 f4
// -> 2-way (free) LDS bank access both phases, no swizzle needed.
// XCD-bijective remap (2016 = 8*252): ph-neighbors (8 shared rows) and
// half-pairs stay on one XCD for L2/L3 read reuse.

#define BB 16
#define CC 3
#define NH 63
#define NW 63
#define NP (NH * NW)
#define TPB 512

typedef float f4 __attribute__((ext_vector_type(4)));

__global__ __launch_bounds__(TPB) void extract_patches_v5(
    const float* __restrict__ x, float* __restrict__ out) {
  __shared__ f4 lds[CC * 16 * 66];  // 3168 f4 = 50688 B -> 3 blocks/CU

  // XCD-bijective remap: 2016 blocks = 8 XCDs * 252.
  unsigned blk = blockIdx.x;
  unsigned id = (blk & 7u) * 252u + (blk >> 3);

  unsigned half = id & 1u;          // pw in [0,32) or [32,63)
  unsigned w = id >> 1;
  unsigned ph = w % NH;
  unsigned b = w / NH;
  unsigned tid = threadIdx.x;

  unsigned pw0 = half ? 32u : 0u;
  unsigned c0  = half ? 64u : 0u;   // f4 column base in the input row
  unsigned ncv = half ? 64u : 66u;  // valid f4 cols staged per row
  unsigned npw = half ? 31u : 32u;  // patches emitted

  // ---- Stage: rows [8ph, 8ph+16) x f4-cols [c0, c0+ncv) of all 3 planes.
  // lds layout: c*1056 + row*66 + col  (== linear s, by construction)
  const f4* src = reinterpret_cast<const f4*>(x);
  unsigned srow = 8u * ph;
  for (unsigned s = tid; s < CC * 16u * 66u; s += TPB) {
    unsigned c = s / 1056u;
    unsigned rem = s - c * 1056u;
    unsigned row = rem / 66u;
    unsigned col = rem - row * 66u;
    if (col < ncv)
      lds[s] = src[(b * CC + c) * 65536u + (srow + row) * 128u + c0 + col];
  }
  __syncthreads();

  // ---- Emit: npw patches * 3 c * 64 f4 — one LINEAR stream per block.
  // e = (pwL*3 + c)*64 + i*4 + j4 ; out f4 = obase + e
  f4* o = reinterpret_cast<f4*>(out) +
          ((size_t)b * NP + (size_t)ph * NW + pw0) * (CC * 64u);
  unsigned ecnt = npw * (CC * 64u);
  for (unsigned e = tid; e < ecnt; e += TPB) {
    unsigned q = e >> 6;            // pwL*3 + c
    unsigned r = e & 63u;
    unsigned pwL = q / 3u;
    unsigned c = q - pwL * 3u;
    unsigned i = r >> 2;
    unsigned j4 = r & 3u;
    o[e] = lds[c * 1056u + i * 66u + 2u * pwL + j4];
  }
}

extern "C" void kernel_launch(void* const* d_in, const int* in_sizes, int n_in,
                              void* d_out, int out_size, void* d_ws, size_t ws_size,
                              hipStream_t stream) {
  const float* x = (const float*)d_in[0];
  float* out = (float*)d_out;
  extract_patches_v5<<<dim3(BB * NH * 2), TPB, 0, stream>>>(x, out);
}